// Round 3
// baseline (4164.680 us; speedup 1.0000x reference)
//
#include <hip/hip_runtime.h>

#define TWO_PI 6.2831853071795864769f
#define SP3 327680      // 128*128*20
#define YT 2560         // 128*20

static __device__ __forceinline__ float gelu_f(float u){
  return 0.5f*u*(1.0f+erff(u*0.7071067811865475f));
}

// ---------------- fc0: x(B,X,Y,T,5) @ (5,20) + b -> h(B,32stride,X,Y,T), 20 ch ----
__global__ void k_fc0(const float* __restrict__ x, const float* __restrict__ w,
                      const float* __restrict__ bias, float* __restrict__ h){
  __shared__ float wl[100], bl[20];
  int tid=threadIdx.x;
  if(tid<100) wl[tid]=w[tid];
  if(tid<20) bl[tid]=bias[tid];
  __syncthreads();
  int p=blockIdx.x*256+tid;          // 0..1310719
  int b=p/SP3, sp=p-b*SP3;
  const float* xp=x+(long)p*5;
  float xi[5];
  #pragma unroll
  for(int i=0;i<5;i++) xi[i]=xp[i];
  float* hb=h+(long)(b*32)*SP3+sp;
  #pragma unroll
  for(int c=0;c<20;c++){
    float a=bl[c];
    #pragma unroll
    for(int i=0;i<5;i++) a+=xi[i]*wl[i*20+c];
    hb[(long)c*SP3]=a;
  }
}

// ------------- forward T+Y DFT over 8-x slabs.
// block: 512 threads; grid: nb*Ci*16. decode: xg=bid&15, bc=bid>>4, c=bc%Ci, b=bc/Ci.
// out: Fty[(b*32+c)*128+x][slot2*8+kz] as float2.
template<int M2>
__global__ __launch_bounds__(512,4) void k_fwd_ty8(const float* __restrict__ h,
                                                   float* __restrict__ Fty, int Ci){
  constexpr int J=2*M2*8;
  __shared__ float Gre[128*65], Gim[128*65];
  __shared__ __align__(16) float2 tw20[160];
  __shared__ float2 tw128[128];
  int tid=threadIdx.x;
  int bid=blockIdx.x;
  int xg=bid&15, bc=bid>>4; int c=bc%Ci, b=bc/Ci;
  int x0=xg*8;
  for(int i=tid;i<160;i+=512){ int t=i>>3,kz=i&7; float s,cc;
    sincosf(TWO_PI*((kz*t)%20)/20.0f,&s,&cc); tw20[i]=make_float2(cc,s); }
  if(tid<128){ float s,cc; sincosf(TWO_PI*tid/128.0f,&s,&cc); tw128[tid]=make_float2(cc,s); }
  __syncthreads();
  // phase 1: T-DFT in registers. thread: xl=tid>>6 (wave-uniform), y = (tid&63)+64k.
  int xl=tid>>6;
  int y0=tid&63;
  const float* hb=h+(long)(b*32+c)*SP3+(x0+xl)*YT;
  const float4* twp=(const float4*)tw20;   // [t*4+q] -> (c,s) for kz=2q,2q+1
  #pragma unroll
  for(int k=0;k<2;k++){
    int y=y0+64*k;
    const float* rp=hb+y*20;
    float4 r0=*(const float4*)(rp);
    float4 r1=*(const float4*)(rp+4);
    float4 r2=*(const float4*)(rp+8);
    float4 r3=*(const float4*)(rp+12);
    float4 r4=*(const float4*)(rp+16);
    float row[20]={r0.x,r0.y,r0.z,r0.w, r1.x,r1.y,r1.z,r1.w, r2.x,r2.y,r2.z,r2.w,
                   r3.x,r3.y,r3.z,r3.w, r4.x,r4.y,r4.z,r4.w};
    float re[8],im[8];
    #pragma unroll
    for(int kz=0;kz<8;kz++){re[kz]=0.f;im[kz]=0.f;}
    #pragma unroll
    for(int t=0;t<20;t++){
      float v=row[t];
      #pragma unroll
      for(int q=0;q<4;q++){
        float4 w=twp[t*4+q];
        re[2*q]  +=v*w.x; im[2*q]  -=v*w.y;
        re[2*q+1]+=v*w.z; im[2*q+1]-=v*w.w;
      }
    }
    #pragma unroll
    for(int kz=0;kz<8;kz++){
      Gre[y*65+xl*8+kz]=re[kz];
      Gim[y*65+xl*8+kz]=im[kz];
    }
  }
  __syncthreads();
  // phase 2: Y-DFT. wave wv handles slots [wv*spw, ...). lanes = (x,kz).
  constexpr int SPW=(2*M2)/8;   // 2 or 3
  int wv=tid>>6, l=tid&63;
  int xl3=l>>3, kz3=l&7;
  float accr[SPW], acci[SPW];
  int km[SPW], jj[SPW];
  #pragma unroll
  for(int si=0;si<SPW;si++){
    int s=wv*SPW+si;
    km[si]=(s<M2)?s:(s-2*M2);
    jj[si]=0; accr[si]=0.f; acci[si]=0.f;
  }
  for(int y=0;y<128;y++){
    float ar=Gre[y*65+l], ai=Gim[y*65+l];
    #pragma unroll
    for(int si=0;si<SPW;si++){
      float2 w=tw128[jj[si]];
      accr[si]+=ar*w.x+ai*w.y;
      acci[si]+=ai*w.x-ar*w.y;
      jj[si]=(jj[si]+km[si])&127;
    }
  }
  float2* outp=(float2*)Fty+((long)(b*32+c)*128+x0+xl3)*J;
  #pragma unroll
  for(int si=0;si<SPW;si++){
    int s=wv*SPW+si;
    outp[s*8+kz3]=make_float2(accr[si],acci[si]);
  }
}

// ------------- forward X DFT: Fty[(b*32+c)*128+x, J] -> Fm[(b*32+c), slot1, J]
template<int M1>
__global__ void k_fwd_x(const float* __restrict__ Fty, float* __restrict__ Fm,
                        int Ci, int m2){
  int bid=blockIdx.x; int c=bid%Ci; int b=bid/Ci;
  int J=2*m2*8;
  __shared__ float tile[32*192*2];
  __shared__ float c128[128], s128[128];
  int tid=threadIdx.x;
  if(tid<128){ float s,cc; sincosf(TWO_PI*tid/128.0f,&s,&cc); c128[tid]=cc; s128[tid]=s; }
  float accre[2*M1], accim[2*M1];
  #pragma unroll
  for(int s=0;s<2*M1;s++){accre[s]=0.f;accim[s]=0.f;}
  for(int xt=0;xt<4;xt++){
    __syncthreads();
    const float* src=Fty+((long)(b*32+c)*128+xt*32)*J*2;
    for(int i=tid;i<32*J*2;i+=256) tile[i]=src[i];
    __syncthreads();
    if(tid<J){
      for(int xl=0;xl<32;xl++){
        int xg=xt*32+xl;
        float ar=tile[(xl*J+tid)*2], ai=tile[(xl*J+tid)*2+1];
        #pragma unroll
        for(int s=0;s<2*M1;s++){
          int km=(s<M1)?s:(s-2*M1);
          int j=(km*xg)&127; float cc=c128[j], ss=s128[j];
          accre[s]+=ar*cc+ai*ss;
          accim[s]+=ai*cc-ar*ss;
        }
      }
    }
  }
  if(tid<J){
    float* o=Fm+(long)(b*32+c)*(2*M1)*J*2;
    #pragma unroll
    for(int s=0;s<2*M1;s++){
      o[(s*J+tid)*2]=accre[s];
      o[(s*J+tid)*2+1]=accim[s];
    }
  }
}

// ------------- mode mixing (unchanged)
__global__ void k_mix(const float* __restrict__ Fm, const float* __restrict__ w,
                      float* __restrict__ Fm2, int Ci, int Co, int m1, int m2){
  int MC=m1*m2*8;
  int nch=MC/8;
  int bid=blockIdx.x;
  int chunk=bid%nch; int q=(bid/nch)&3; int b=bid/(4*nch);
  int tid=threadIdx.x;
  int M1S=2*m1, M2S=2*m2;
  int J=M2S*8;
  __shared__ float fin[32*16];
  for(int idx=tid;idx<Ci*16;idx+=blockDim.x){
    int i=idx>>4; int r=idx&15; int mll=r>>1; int ri=r&1;
    int mg=chunk*8+mll;
    int mx=mg/(m2*8); int my=(mg>>3)%m2; int kz=mg&7;
    int sx=(q&1)?(m1+mx):mx; int sy=(q&2)?(m2+my):my;
    fin[idx]=Fm[((long)((b*32+i)*M1S+sx)*J+sy*8+kz)*2+ri];
  }
  __syncthreads();
  int ml=tid&7, o=tid>>3;
  int mg=chunk*8+ml;
  int mx=mg/(m2*8); int my=(mg>>3)%m2; int kz=mg&7;
  int sx=(q&1)?(m1+mx):mx; int sy=(q&2)?(m2+my):my;
  int moff=(mx*m2+my)*8+kz;
  const float* wr=w+(long)(q*2)*Ci*Co*MC+o*MC+moff;
  const float* wi=wr+(long)Ci*Co*MC;
  long wstep=(long)Co*MC;
  float re=0.f, im=0.f;
  for(int i=0;i<Ci;i++){
    float ar=fin[i*16+ml*2], ai=fin[i*16+ml*2+1];
    float wrv=wr[i*wstep], wiv=wi[i*wstep];
    re+=ar*wrv-ai*wiv;
    im+=ar*wiv+ai*wrv;
  }
  long oidx=((long)((b*32+o)*M1S+sx)*J+sy*8+kz)*2;
  Fm2[oidx]=re; Fm2[oidx+1]=im;
}

// ------------- inverse X (unchanged): Fm2[(b*32+o),slot1,J] -> g1[(b*32+o)*128+x, J]
__global__ void k_inv_x(const float* __restrict__ Fm2, float* __restrict__ g1,
                        int Co, int m1, int m2){
  int bid=blockIdx.x; int xt=bid&3; int oc=(bid>>2)%Co; int b=bid/(4*Co);
  int M1S=2*m1; int J=2*m2*8;
  __shared__ float slab[24*192*2];
  __shared__ float c128[128], s128[128];
  int tid=threadIdx.x;
  if(tid<128){ float s,cc; sincosf(TWO_PI*tid/128.0f,&s,&cc); c128[tid]=cc; s128[tid]=s; }
  const float* src=Fm2+(long)(b*32+oc)*M1S*J*2;
  for(int i=tid;i<M1S*J*2;i+=256) slab[i]=src[i];
  __syncthreads();
  for(int out=tid;out<32*J;out+=256){
    int xl=out/J; int j=out-xl*J; int xg=xt*32+xl;
    float re=0.f, im=0.f;
    for(int s=0;s<M1S;s++){
      int km=(s<m1)?s:(s-2*m1);
      int jjx=(km*xg)&127; float cc=c128[jjx], ss=s128[jjx];
      float ar=slab[(s*J+j)*2], ai=slab[(s*J+j)*2+1];
      re+=ar*cc-ai*ss;
      im+=ar*ss+ai*cc;
    }
    long oidx=((long)((b*32+oc)*128+xg)*J+j)*2;
    g1[oidx]=re; g1[oidx+1]=im;
  }
}

// ------------- inverse Y + inverse T + add into h + (gelu), 8-x slabs.
// block: 512 threads; grid: nb*Co*16. g1: float2 rows [(b*32+oc)*128+x][J].
template<int M2>
__global__ __launch_bounds__(512,4) void k_inv_yt8(const float* __restrict__ g1,
                                                   float* h, int Co, int do_gelu){
  constexpr int J=2*M2*8;
  constexpr int S2=2*M2;
  __shared__ float Gre[128*65], Gim[128*65];
  __shared__ float2 g1s[S2*64];
  __shared__ __align__(16) float2 tw20[160];
  __shared__ float2 tw128[128];
  int tid=threadIdx.x;
  int bid=blockIdx.x;
  int xg=bid&15, bo=bid>>4; int oc=bo%Co, b=bo/Co;
  int x0=xg*8;
  for(int i=tid;i<160;i+=512){ int t=i>>3,kz=i&7; float s,cc;
    sincosf(TWO_PI*((kz*t)%20)/20.0f,&s,&cc); tw20[i]=make_float2(cc,s); }
  if(tid<128){ float s,cc; sincosf(TWO_PI*tid/128.0f,&s,&cc); tw128[tid]=make_float2(cc,s); }
  // stage g1 slab into LDS as [slot][x*8+kz]
  const float2* g1p=(const float2*)g1+((long)(b*32+oc)*128+x0)*J;
  for(int idx=tid;idx<8*J;idx+=512){
    int x=idx/J, j=idx-x*J;
    int s=j>>3, kz=j&7;
    g1s[s*64+x*8+kz]=g1p[x*J+j];
  }
  __syncthreads();
  // phase A: inverse Y. wave wv -> y in [wv*16, wv*16+16). lanes = (x,kz).
  int wv=tid>>6, l=tid&63;
  {
    float gyr[16], gyi[16];
    #pragma unroll
    for(int i=0;i<16;i++){gyr[i]=0.f;gyi[i]=0.f;}
    int ybase=wv*16;
    for(int s=0;s<S2;s++){
      int km=(s<M2)?s:(s-S2);
      float2 d=g1s[s*64+l];
      int jj=(km*ybase)&127;
      #pragma unroll
      for(int yy=0;yy<16;yy++){
        float2 w=tw128[jj];
        gyr[yy]+=d.x*w.x-d.y*w.y;
        gyi[yy]+=d.x*w.y+d.y*w.x;
        jj=(jj+km)&127;
      }
    }
    #pragma unroll
    for(int yy=0;yy<16;yy++){
      Gre[(ybase+yy)*65+l]=gyr[yy];
      Gim[(ybase+yy)*65+l]=gyi[yy];
    }
  }
  __syncthreads();
  // phase B: inverse T + add + gelu. thread rows: r=k*512+tid -> y=r&127, xl=r>>7.
  const float invN=1.0f/(128.0f*128.0f*20.0f);
  float* hb=h+(long)(b*32+oc)*SP3+x0*YT;
  #pragma unroll
  for(int k=0;k<2;k++){
    int r=k*512+tid;
    int y=r&127, xl=r>>7;
    float gr[8],gi[8];
    #pragma unroll
    for(int kz=0;kz<8;kz++){gr[kz]=Gre[y*65+xl*8+kz];gi[kz]=Gim[y*65+xl*8+kz];}
    float* hp=hb+xl*YT+y*20;
    float o[20];
    #pragma unroll
    for(int t=0;t<20;t++){
      float v=gr[0];
      #pragma unroll
      for(int kz=1;kz<8;kz++){
        float2 w=tw20[t*8+kz];
        v+=2.0f*(gr[kz]*w.x-gi[kz]*w.y);
      }
      o[t]=v*invN;
    }
    #pragma unroll
    for(int q=0;q<5;q++){
      float4 hv=*(const float4*)(hp+q*4);
      float4 ov;
      ov.x=hv.x+o[q*4+0]; ov.y=hv.y+o[q*4+1]; ov.z=hv.z+o[q*4+2]; ov.w=hv.w+o[q*4+3];
      if(do_gelu){ov.x=gelu_f(ov.x);ov.y=gelu_f(ov.y);ov.z=gelu_f(ov.z);ov.w=gelu_f(ov.w);}
      *(float4*)(hp+q*4)=ov;
    }
  }
}

// ------------- pointwise conv IN-PLACE, 2 points/thread, float4 weight broadcasts.
template<int CO>
__global__ __launch_bounds__(256,4) void k_pconv2(float* h, const float* __restrict__ w,
                                                  const float* __restrict__ bias, int Ci){
  __shared__ __align__(16) float wt[32*CO];   // [i][o]
  __shared__ float bl[CO];
  int tid=threadIdx.x;
  for(int idx=tid;idx<Ci*CO;idx+=256){int i=idx/CO,o=idx-i*CO; wt[idx]=w[o*Ci+i];}
  if(tid<CO) bl[tid]=bias[tid];
  __syncthreads();
  long p=(long)blockIdx.x*512+tid;   // points p, p+256 (same batch: SP3%512==0)
  int b=(int)(p/SP3); int sp=(int)(p-(long)b*SP3);
  float* hb=h+(long)b*32*SP3+sp;
  float acc0[CO],acc1[CO];
  #pragma unroll
  for(int o=0;o<CO;o++){acc0[o]=bl[o];acc1[o]=bl[o];}
  for(int i=0;i<Ci;i++){
    float v0=hb[(long)i*SP3];
    float v1=hb[(long)i*SP3+256];
    const float4* wc=(const float4*)&wt[i*CO];
    #pragma unroll
    for(int o4=0;o4<CO/4;o4++){
      float4 ww=wc[o4];
      acc0[4*o4+0]+=v0*ww.x; acc0[4*o4+1]+=v0*ww.y;
      acc0[4*o4+2]+=v0*ww.z; acc0[4*o4+3]+=v0*ww.w;
      acc1[4*o4+0]+=v1*ww.x; acc1[4*o4+1]+=v1*ww.y;
      acc1[4*o4+2]+=v1*ww.z; acc1[4*o4+3]+=v1*ww.w;
    }
  }
  #pragma unroll
  for(int o=0;o<CO;o++){hb[(long)o*SP3]=acc0[o]; hb[(long)o*SP3+256]=acc1[o];}
}

// ------------- head: fc1(32->128)+gelu, fc2(128->3). 2 points/thread.
__global__ __launch_bounds__(256,4) void k_head2(const float* __restrict__ h,
                       const float* __restrict__ w1, const float* __restrict__ b1,
                       const float* __restrict__ w2, const float* __restrict__ b2,
                       float* __restrict__ out){
  __shared__ __align__(16) float w1t[128*32];   // [jj][i]
  __shared__ float b1l[128];
  __shared__ __align__(16) float4 w2l[128];
  __shared__ float b2l[3];
  int tid=threadIdx.x;
  for(int idx=tid;idx<4096;idx+=256){int jj=idx>>5,i=idx&31; w1t[idx]=w1[i*128+jj];}
  if(tid<128){b1l[tid]=b1[tid]; w2l[tid]=make_float4(w2[tid*3],w2[tid*3+1],w2[tid*3+2],0.f);}
  if(tid<3) b2l[tid]=b2[tid];
  __syncthreads();
  long p=(long)blockIdx.x*512+tid;
  int b=(int)(p/SP3); int sp=(int)(p-(long)b*SP3);
  const float* hb=h+(long)b*32*SP3+sp;
  float hv0[32],hv1[32];
  #pragma unroll
  for(int i=0;i<32;i++){hv0[i]=hb[(long)i*SP3]; hv1[i]=hb[(long)i*SP3+256];}
  float a00=b2l[0],a01=b2l[1],a02=b2l[2];
  float a10=b2l[0],a11=b2l[1],a12=b2l[2];
  for(int jj=0;jj<128;jj++){
    const float4* wc=(const float4*)&w1t[jj*32];
    float u0=b1l[jj], u1=b1l[jj];
    #pragma unroll
    for(int q=0;q<8;q++){
      float4 ww=wc[q];
      u0+=hv0[4*q]*ww.x+hv0[4*q+1]*ww.y+hv0[4*q+2]*ww.z+hv0[4*q+3]*ww.w;
      u1+=hv1[4*q]*ww.x+hv1[4*q+1]*ww.y+hv1[4*q+2]*ww.z+hv1[4*q+3]*ww.w;
    }
    u0=gelu_f(u0); u1=gelu_f(u1);
    float4 w2v=w2l[jj];
    a00+=u0*w2v.x; a01+=u0*w2v.y; a02+=u0*w2v.z;
    a10+=u1*w2v.x; a11+=u1*w2v.y; a12+=u1*w2v.z;
  }
  float* op=out+p*3;
  op[0]=a00; op[1]=a01; op[2]=a02;
  float* op1=out+(p+256)*3;
  op1[0]=a10; op1[1]=a11; op1[2]=a12;
}

extern "C" void kernel_launch(void* const* d_in, const int* in_sizes, int n_in,
                              void* d_out, int out_size, void* d_ws, size_t ws_size,
                              hipStream_t stream){
  (void)in_sizes; (void)n_in; (void)out_size;
  const float* x    =(const float*)d_in[0];
  const float* fc0w =(const float*)d_in[1];
  const float* fc0b =(const float*)d_in[2];
  const float* sw[4]={(const float*)d_in[3],(const float*)d_in[6],(const float*)d_in[9],(const float*)d_in[12]};
  const float* cw[4]={(const float*)d_in[4],(const float*)d_in[7],(const float*)d_in[10],(const float*)d_in[13]};
  const float* cb[4]={(const float*)d_in[5],(const float*)d_in[8],(const float*)d_in[11],(const float*)d_in[14]};
  const float* fc1w =(const float*)d_in[15];
  const float* fc1b =(const float*)d_in[16];
  const float* fc2w =(const float*)d_in[17];
  const float* fc2b =(const float*)d_in[18];
  float* out=(float*)d_out;
  float* ws=(float*)d_ws;

  const long H_FLOATS   = 41943040L;            // 4*32*327680 (168 MB)
  const long FTY_FULL   = 6291456L;             // 4*32*128*192*2
  const long FM_FULL    = 1179648L;             // 4*32*24*192*2
  const long NEED_FULL  = H_FLOATS + FTY_FULL + 2*FM_FULL;

  float* h = ws;
  bool full = (ws_size >= (size_t)NEED_FULL*4);

  const int LAY[5]={20,24,24,32,32};
  const int M1A[4]={8,8,12,12};

  k_fc0<<<5120,256,0,stream>>>(x,fc0w,fc0b,h);

  for(int L=0;L<4;L++){
    int Ci=LAY[L], Co=LAY[L+1], m1=M1A[L], m2=M1A[L];
    int nch=m1*m2;
    long FM_B=(long)32*(2*m1)*(2*m2*8)*2;

    if(full){
      float* Fty=ws+H_FLOATS;
      float* Fm =ws+H_FLOATS+FTY_FULL;
      float* Fm2=ws+H_FLOATS+FTY_FULL+FM_FULL;
      if(m1==8)  k_fwd_ty8<8> <<<4*Ci*16,512,0,stream>>>(h,Fty,Ci);
      else       k_fwd_ty8<12><<<4*Ci*16,512,0,stream>>>(h,Fty,Ci);
      if(m1==8)  k_fwd_x<8> <<<4*Ci,256,0,stream>>>(Fty,Fm,Ci,m2);
      else       k_fwd_x<12><<<4*Ci,256,0,stream>>>(Fty,Fm,Ci,m2);
      k_mix<<<4*4*nch,Co*8,0,stream>>>(Fm,sw[L],Fm2,Ci,Co,m1,m2);
      if(Co==24) k_pconv2<24><<<2560,256,0,stream>>>(h,cw[L],cb[L],Ci);
      else       k_pconv2<32><<<2560,256,0,stream>>>(h,cw[L],cb[L],Ci);
      k_inv_x<<<4*Co*4,256,0,stream>>>(Fm2,Fty,Co,m1,m2);     // g1 aliases Fty
      if(m1==8)  k_inv_yt8<8> <<<4*Co*16,512,0,stream>>>(Fty,h,Co,(L!=3)?1:0);
      else       k_inv_yt8<12><<<4*Co*16,512,0,stream>>>(Fty,h,Co,(L!=3)?1:0);
    } else {
      // scratch lives in d_out (rewritten entirely by k_head at the end)
      float* Fty=out;                 // <= 1,572,864 floats
      float* Fm =out+1572864;         // <=   294,912 floats
      float* Fm2=out+1867776;         // <= 1,179,648 floats (per-b strided)
      for(int b=0;b<4;b++){
        float* hbp=h+(long)b*32*SP3;
        if(m1==8)  k_fwd_ty8<8> <<<Ci*16,512,0,stream>>>(hbp,Fty,Ci);
        else       k_fwd_ty8<12><<<Ci*16,512,0,stream>>>(hbp,Fty,Ci);
        if(m1==8)  k_fwd_x<8> <<<Ci,256,0,stream>>>(Fty,Fm,Ci,m2);
        else       k_fwd_x<12><<<Ci,256,0,stream>>>(Fty,Fm,Ci,m2);
        k_mix<<<4*nch,Co*8,0,stream>>>(Fm,sw[L],Fm2+b*FM_B,Ci,Co,m1,m2);
      }
      if(Co==24) k_pconv2<24><<<2560,256,0,stream>>>(h,cw[L],cb[L],Ci);
      else       k_pconv2<32><<<2560,256,0,stream>>>(h,cw[L],cb[L],Ci);
      for(int b=0;b<4;b++){
        float* hbp=h+(long)b*32*SP3;
        k_inv_x<<<Co*4,256,0,stream>>>(Fm2+b*FM_B,Fty,Co,m1,m2);
        if(m1==8)  k_inv_yt8<8> <<<Co*16,512,0,stream>>>(Fty,hbp,Co,(L!=3)?1:0);
        else       k_inv_yt8<12><<<Co*16,512,0,stream>>>(Fty,hbp,Co,(L!=3)?1:0);
      }
    }
  }
  k_head2<<<2560,256,0,stream>>>(h,fc1w,fc1b,fc2w,fc2b,out);
}

// Round 4
// 2089.518 us; speedup vs baseline: 1.9931x; 1.9931x over previous
//
#include <hip/hip_runtime.h>

#define TWO_PI 6.2831853071795864769f
#define SP3 327680      // 128*128*20
#define YT 2560         // 128*20

static __device__ __forceinline__ float gelu_f(float u){
  return 0.5f*u*(1.0f+erff(u*0.7071067811865475f));
}

// ---------------- fc0: x(B,X,Y,T,5) @ (5,20) + b -> h(B,32stride,X,Y,T), 20 ch ----
__global__ void k_fc0(const float* __restrict__ x, const float* __restrict__ w,
                      const float* __restrict__ bias, float* __restrict__ h){
  __shared__ float wl[100], bl[20];
  int tid=threadIdx.x;
  if(tid<100) wl[tid]=w[tid];
  if(tid<20) bl[tid]=bias[tid];
  __syncthreads();
  int p=blockIdx.x*256+tid;          // 0..1310719
  int b=p/SP3, sp=p-b*SP3;
  const float* xp=x+(long)p*5;
  float xi[5];
  #pragma unroll
  for(int i=0;i<5;i++) xi[i]=xp[i];
  float* hb=h+(long)(b*32)*SP3+sp;
  #pragma unroll
  for(int c=0;c<20;c++){
    float a=bl[c];
    #pragma unroll
    for(int i=0;i<5;i++) a+=xi[i]*wl[i*20+c];
    hb[(long)c*SP3]=a;
  }
}

// ------------- forward T+Y DFT over 8-x slabs, coalesced staging, 2 xl-halves.
// block: 512 threads; grid: nb*Ci*16. out: Fty[(b*32+c)*128+x][slot2*8+kz] float2.
template<int M2>
__global__ __launch_bounds__(512,4) void k_fwd_ty8(const float* __restrict__ h,
                                                   float* __restrict__ Fty, int Ci){
  constexpr int J=2*M2*8;
  constexpr int ITEMS=2*M2*32;          // (slot, xl(4), kz(8)) items per half
  __shared__ float slab[512*21];        // 43008 B, rows padded to 21
  __shared__ float2 Gc[128*33];         // 33792 B, [y][col=xl*8+kz], pad 33
  __shared__ __align__(16) float2 tw20[160];
  __shared__ float2 tw128[128];
  int tid=threadIdx.x;
  int bid=blockIdx.x;
  int xg=bid&15, bc=bid>>4; int c=bc%Ci, b=bc/Ci;
  int x0=xg*8;
  for(int i=tid;i<160;i+=512){ int t=i>>3,kz=i&7; float s,cc;
    sincosf(TWO_PI*((kz*t)%20)/20.0f,&s,&cc); tw20[i]=make_float2(cc,s); }
  if(tid<128){ float s,cc; sincosf(TWO_PI*tid/128.0f,&s,&cc); tw128[tid]=make_float2(cc,s); }
  const float* hb=h+(long)(b*32+c)*SP3+x0*YT;
  float2* outp=(float2*)Fty+((long)(b*32+c)*128+x0)*J;
  const float4* twp=(const float4*)tw20;   // [t*4+q] -> (c,s) for kz=2q,2q+1

  for(int half=0;half<2;half++){
    __syncthreads();                      // protect slab/Gc from prev half readers
    // ---- coalesced stage: 10240 floats (xl_local 0..3)
    const float* src=hb+half*10240;
    for(int f=tid;f<10240;f+=512){
      int r=f/20, t=f-r*20;               // r = xl_local*128+y
      slab[r*21+t]=src[f];
    }
    __syncthreads();
    // ---- T-DFT: one row per thread
    {
      int r=tid; int y=r&127, xl=r>>7;
      float row[20];
      #pragma unroll
      for(int t=0;t<20;t++) row[t]=slab[r*21+t];
      float re[8],im[8];
      #pragma unroll
      for(int kz=0;kz<8;kz++){re[kz]=0.f;im[kz]=0.f;}
      #pragma unroll
      for(int t=0;t<20;t++){
        float v=row[t];
        #pragma unroll
        for(int q=0;q<4;q++){
          float4 w=twp[t*4+q];
          re[2*q]  +=v*w.x; im[2*q]  -=v*w.y;
          re[2*q+1]+=v*w.z; im[2*q+1]-=v*w.w;
        }
      }
      #pragma unroll
      for(int kz=0;kz<8;kz++) Gc[y*33+xl*8+kz]=make_float2(re[kz],im[kz]);
    }
    __syncthreads();
    // ---- Y-DFT: item = (slot s, col=(xl,kz)), incremental twiddle
    for(int idx=tid;idx<ITEMS;idx+=512){
      int col=idx&31, s=idx>>5;
      int xl=col>>3, kz=col&7;
      int km=(s<M2)?s:(s-2*M2);
      float accr=0.f, acci=0.f; int jj=0;
      for(int y=0;y<128;y++){
        float2 w=tw128[jj];
        float2 d=Gc[y*33+col];
        accr+=d.x*w.x+d.y*w.y;
        acci+=d.y*w.x-d.x*w.y;
        jj=(jj+km)&127;
      }
      outp[(long)(half*4+xl)*J+s*8+kz]=make_float2(accr,acci);
    }
  }
}

// ------------- forward X DFT: Fty[(b*32+c)*128+x, J] -> Fm[(b*32+c), slot1, J]
template<int M1>
__global__ void k_fwd_x(const float* __restrict__ Fty, float* __restrict__ Fm,
                        int Ci, int m2){
  int bid=blockIdx.x; int c=bid%Ci; int b=bid/Ci;
  int J=2*m2*8;
  __shared__ float tile[32*192*2];
  __shared__ float c128[128], s128[128];
  int tid=threadIdx.x;
  if(tid<128){ float s,cc; sincosf(TWO_PI*tid/128.0f,&s,&cc); c128[tid]=cc; s128[tid]=s; }
  float accre[2*M1], accim[2*M1];
  #pragma unroll
  for(int s=0;s<2*M1;s++){accre[s]=0.f;accim[s]=0.f;}
  for(int xt=0;xt<4;xt++){
    __syncthreads();
    const float* src=Fty+((long)(b*32+c)*128+xt*32)*J*2;
    for(int i=tid;i<32*J*2;i+=256) tile[i]=src[i];
    __syncthreads();
    if(tid<J){
      for(int xl=0;xl<32;xl++){
        int xg=xt*32+xl;
        float ar=tile[(xl*J+tid)*2], ai=tile[(xl*J+tid)*2+1];
        #pragma unroll
        for(int s=0;s<2*M1;s++){
          int km=(s<M1)?s:(s-2*M1);
          int j=(km*xg)&127; float cc=c128[j], ss=s128[j];
          accre[s]+=ar*cc+ai*ss;
          accim[s]+=ai*cc-ar*ss;
        }
      }
    }
  }
  if(tid<J){
    float* o=Fm+(long)(b*32+c)*(2*M1)*J*2;
    #pragma unroll
    for(int s=0;s<2*M1;s++){
      o[(s*J+tid)*2]=accre[s];
      o[(s*J+tid)*2+1]=accim[s];
    }
  }
}

// ------------- mode mixing (unchanged)
__global__ void k_mix(const float* __restrict__ Fm, const float* __restrict__ w,
                      float* __restrict__ Fm2, int Ci, int Co, int m1, int m2){
  int MC=m1*m2*8;
  int nch=MC/8;
  int bid=blockIdx.x;
  int chunk=bid%nch; int q=(bid/nch)&3; int b=bid/(4*nch);
  int tid=threadIdx.x;
  int M1S=2*m1, M2S=2*m2;
  int J=M2S*8;
  __shared__ float fin[32*16];
  for(int idx=tid;idx<Ci*16;idx+=blockDim.x){
    int i=idx>>4; int r=idx&15; int mll=r>>1; int ri=r&1;
    int mg=chunk*8+mll;
    int mx=mg/(m2*8); int my=(mg>>3)%m2; int kz=mg&7;
    int sx=(q&1)?(m1+mx):mx; int sy=(q&2)?(m2+my):my;
    fin[idx]=Fm[((long)((b*32+i)*M1S+sx)*J+sy*8+kz)*2+ri];
  }
  __syncthreads();
  int ml=tid&7, o=tid>>3;
  int mg=chunk*8+ml;
  int mx=mg/(m2*8); int my=(mg>>3)%m2; int kz=mg&7;
  int sx=(q&1)?(m1+mx):mx; int sy=(q&2)?(m2+my):my;
  int moff=(mx*m2+my)*8+kz;
  const float* wr=w+(long)(q*2)*Ci*Co*MC+o*MC+moff;
  const float* wi=wr+(long)Ci*Co*MC;
  long wstep=(long)Co*MC;
  float re=0.f, im=0.f;
  for(int i=0;i<Ci;i++){
    float ar=fin[i*16+ml*2], ai=fin[i*16+ml*2+1];
    float wrv=wr[i*wstep], wiv=wi[i*wstep];
    re+=ar*wrv-ai*wiv;
    im+=ar*wiv+ai*wrv;
  }
  long oidx=((long)((b*32+o)*M1S+sx)*J+sy*8+kz)*2;
  Fm2[oidx]=re; Fm2[oidx+1]=im;
}

// ------------- inverse X (unchanged): Fm2[(b*32+o),slot1,J] -> g1[(b*32+o)*128+x, J]
__global__ void k_inv_x(const float* __restrict__ Fm2, float* __restrict__ g1,
                        int Co, int m1, int m2){
  int bid=blockIdx.x; int xt=bid&3; int oc=(bid>>2)%Co; int b=bid/(4*Co);
  int M1S=2*m1; int J=2*m2*8;
  __shared__ float slab[24*192*2];
  __shared__ float c128[128], s128[128];
  int tid=threadIdx.x;
  if(tid<128){ float s,cc; sincosf(TWO_PI*tid/128.0f,&s,&cc); c128[tid]=cc; s128[tid]=s; }
  const float* src=Fm2+(long)(b*32+oc)*M1S*J*2;
  for(int i=tid;i<M1S*J*2;i+=256) slab[i]=src[i];
  __syncthreads();
  for(int out=tid;out<32*J;out+=256){
    int xl=out/J; int j=out-xl*J; int xg=xt*32+xl;
    float re=0.f, im=0.f;
    for(int s=0;s<M1S;s++){
      int km=(s<m1)?s:(s-2*m1);
      int jjx=(km*xg)&127; float cc=c128[jjx], ss=s128[jjx];
      float ar=slab[(s*J+j)*2], ai=slab[(s*J+j)*2+1];
      re+=ar*cc-ai*ss;
      im+=ar*ss+ai*cc;
    }
    long oidx=((long)((b*32+oc)*128+xg)*J+j)*2;
    g1[oidx]=re; g1[oidx+1]=im;
  }
}

// ------------- inverse Y (registers) + inverse T + coalesced RMW add + gelu.
// block: 512 threads; grid: nb*Co*16. g1: float2 rows [(b*32+oc)*128+x][J].
template<int M2>
__global__ __launch_bounds__(512,4) void k_inv_yt8(const float* __restrict__ g1,
                                                   float* h, int Co, int do_gelu){
  constexpr int S2=2*M2;
  constexpr int J=S2*8;
  __shared__ float2 g1s[S2*64];         // [s][xl*8+kz], <=12288 B
  __shared__ float So[512*21];          // out rows, padded, 43008 B
  __shared__ float2 tw20[160];
  __shared__ float2 tw128[128];
  int tid=threadIdx.x;
  int bid=blockIdx.x;
  int xg=bid&15, bo=bid>>4; int oc=bo%Co, b=bo/Co;
  int x0=xg*8;
  for(int i=tid;i<160;i+=512){ int t=i>>3,kz=i&7; float s,cc;
    sincosf(TWO_PI*((kz*t)%20)/20.0f,&s,&cc); tw20[i]=make_float2(cc,s); }
  if(tid<128){ float s,cc; sincosf(TWO_PI*tid/128.0f,&s,&cc); tw128[tid]=make_float2(cc,s); }
  // stage g1 slab (coalesced float2)
  const float2* g1p=(const float2*)g1+((long)(b*32+oc)*128+x0)*J;
  for(int idx=tid;idx<8*J;idx+=512){
    int x=idx/J, j=idx-x*J;
    int s=j>>3, kz=j&7;
    g1s[s*64+x*8+kz]=g1p[idx];
  }
  __syncthreads();
  const float invN=1.0f/(128.0f*128.0f*20.0f);
  float* hb=h+(long)(b*32+oc)*SP3+x0*YT;
  for(int half=0;half<2;half++){
    int y=tid&127;
    int xl=(half*512+tid)>>7;           // wave-uniform: 0..7
    // ---- inverse-Y into registers (g1s reads are wave-uniform broadcasts)
    float gyr[8],gyi[8];
    #pragma unroll
    for(int kz=0;kz<8;kz++){gyr[kz]=0.f;gyi[kz]=0.f;}
    for(int s=0;s<S2;s++){
      int km=(s<M2)?s:(s-S2);
      float2 w=tw128[(km*y)&127];
      #pragma unroll
      for(int kz=0;kz<8;kz++){
        float2 d=g1s[s*64+xl*8+kz];
        gyr[kz]+=d.x*w.x-d.y*w.y;
        gyi[kz]+=d.x*w.y+d.y*w.x;
      }
    }
    // ---- inverse-T to row o[20], store to padded LDS slab
    #pragma unroll
    for(int t=0;t<20;t++){
      float v=gyr[0];
      #pragma unroll
      for(int kz=1;kz<8;kz++){
        float2 w=tw20[t*8+kz];
        v+=2.0f*(gyr[kz]*w.x-gyi[kz]*w.y);
      }
      So[tid*21+t]=v*invN;
    }
    __syncthreads();
    // ---- flat coalesced RMW flush of this half (10240 contiguous floats)
    float* dst=hb+half*10240;
    for(int f=tid;f<10240;f+=512){
      int rr=f/20, t=f-rr*20;
      float u=dst[f]+So[rr*21+t];
      if(do_gelu) u=gelu_f(u);
      dst[f]=u;
    }
    __syncthreads();                    // So reused next half
  }
}

// ------------- pointwise conv IN-PLACE, 2 points/thread, float4 weight broadcasts.
template<int CO>
__global__ __launch_bounds__(256,4) void k_pconv2(float* h, const float* __restrict__ w,
                                                  const float* __restrict__ bias, int Ci){
  __shared__ __align__(16) float wt[32*CO];   // [i][o]
  __shared__ float bl[CO];
  int tid=threadIdx.x;
  for(int idx=tid;idx<Ci*CO;idx+=256){int i=idx/CO,o=idx-i*CO; wt[idx]=w[o*Ci+i];}
  if(tid<CO) bl[tid]=bias[tid];
  __syncthreads();
  long p=(long)blockIdx.x*512+tid;   // points p, p+256 (same batch: SP3%512==0)
  int b=(int)(p/SP3); int sp=(int)(p-(long)b*SP3);
  float* hb=h+(long)b*32*SP3+sp;
  float acc0[CO],acc1[CO];
  #pragma unroll
  for(int o=0;o<CO;o++){acc0[o]=bl[o];acc1[o]=bl[o];}
  for(int i=0;i<Ci;i++){
    float v0=hb[(long)i*SP3];
    float v1=hb[(long)i*SP3+256];
    const float4* wc=(const float4*)&wt[i*CO];
    #pragma unroll
    for(int o4=0;o4<CO/4;o4++){
      float4 ww=wc[o4];
      acc0[4*o4+0]+=v0*ww.x; acc0[4*o4+1]+=v0*ww.y;
      acc0[4*o4+2]+=v0*ww.z; acc0[4*o4+3]+=v0*ww.w;
      acc1[4*o4+0]+=v1*ww.x; acc1[4*o4+1]+=v1*ww.y;
      acc1[4*o4+2]+=v1*ww.z; acc1[4*o4+3]+=v1*ww.w;
    }
  }
  #pragma unroll
  for(int o=0;o<CO;o++){hb[(long)o*SP3]=acc0[o]; hb[(long)o*SP3+256]=acc1[o];}
}

// ------------- head: fc1(32->128)+gelu, fc2(128->3). 2 points/thread.
__global__ __launch_bounds__(256,4) void k_head2(const float* __restrict__ h,
                       const float* __restrict__ w1, const float* __restrict__ b1,
                       const float* __restrict__ w2, const float* __restrict__ b2,
                       float* __restrict__ out){
  __shared__ __align__(16) float w1t[128*32];   // [jj][i]
  __shared__ float b1l[128];
  __shared__ __align__(16) float4 w2l[128];
  __shared__ float b2l[3];
  int tid=threadIdx.x;
  for(int idx=tid;idx<4096;idx+=256){int jj=idx>>5,i=idx&31; w1t[idx]=w1[i*128+jj];}
  if(tid<128){b1l[tid]=b1[tid]; w2l[tid]=make_float4(w2[tid*3],w2[tid*3+1],w2[tid*3+2],0.f);}
  if(tid<3) b2l[tid]=b2[tid];
  __syncthreads();
  long p=(long)blockIdx.x*512+tid;
  int b=(int)(p/SP3); int sp=(int)(p-(long)b*SP3);
  const float* hb=h+(long)b*32*SP3+sp;
  float hv0[32],hv1[32];
  #pragma unroll
  for(int i=0;i<32;i++){hv0[i]=hb[(long)i*SP3]; hv1[i]=hb[(long)i*SP3+256];}
  float a00=b2l[0],a01=b2l[1],a02=b2l[2];
  float a10=b2l[0],a11=b2l[1],a12=b2l[2];
  for(int jj=0;jj<128;jj++){
    const float4* wc=(const float4*)&w1t[jj*32];
    float u0=b1l[jj], u1=b1l[jj];
    #pragma unroll
    for(int q=0;q<8;q++){
      float4 ww=wc[q];
      u0+=hv0[4*q]*ww.x+hv0[4*q+1]*ww.y+hv0[4*q+2]*ww.z+hv0[4*q+3]*ww.w;
      u1+=hv1[4*q]*ww.x+hv1[4*q+1]*ww.y+hv1[4*q+2]*ww.z+hv1[4*q+3]*ww.w;
    }
    u0=gelu_f(u0); u1=gelu_f(u1);
    float4 w2v=w2l[jj];
    a00+=u0*w2v.x; a01+=u0*w2v.y; a02+=u0*w2v.z;
    a10+=u1*w2v.x; a11+=u1*w2v.y; a12+=u1*w2v.z;
  }
  float* op=out+p*3;
  op[0]=a00; op[1]=a01; op[2]=a02;
  float* op1=out+(p+256)*3;
  op1[0]=a10; op1[1]=a11; op1[2]=a12;
}

extern "C" void kernel_launch(void* const* d_in, const int* in_sizes, int n_in,
                              void* d_out, int out_size, void* d_ws, size_t ws_size,
                              hipStream_t stream){
  (void)in_sizes; (void)n_in; (void)out_size;
  const float* x    =(const float*)d_in[0];
  const float* fc0w =(const float*)d_in[1];
  const float* fc0b =(const float*)d_in[2];
  const float* sw[4]={(const float*)d_in[3],(const float*)d_in[6],(const float*)d_in[9],(const float*)d_in[12]};
  const float* cw[4]={(const float*)d_in[4],(const float*)d_in[7],(const float*)d_in[10],(const float*)d_in[13]};
  const float* cb[4]={(const float*)d_in[5],(const float*)d_in[8],(const float*)d_in[11],(const float*)d_in[14]};
  const float* fc1w =(const float*)d_in[15];
  const float* fc1b =(const float*)d_in[16];
  const float* fc2w =(const float*)d_in[17];
  const float* fc2b =(const float*)d_in[18];
  float* out=(float*)d_out;
  float* ws=(float*)d_ws;

  const long H_FLOATS   = 41943040L;            // 4*32*327680 (168 MB)
  const long FTY_FULL   = 6291456L;             // 4*32*128*192*2
  const long FM_FULL    = 1179648L;             // 4*32*24*192*2
  const long NEED_FULL  = H_FLOATS + FTY_FULL + 2*FM_FULL;

  float* h = ws;
  bool full = (ws_size >= (size_t)NEED_FULL*4);

  const int LAY[5]={20,24,24,32,32};
  const int M1A[4]={8,8,12,12};

  k_fc0<<<5120,256,0,stream>>>(x,fc0w,fc0b,h);

  for(int L=0;L<4;L++){
    int Ci=LAY[L], Co=LAY[L+1], m1=M1A[L], m2=M1A[L];
    int nch=m1*m2;
    long FM_B=(long)32*(2*m1)*(2*m2*8)*2;

    if(full){
      float* Fty=ws+H_FLOATS;
      float* Fm =ws+H_FLOATS+FTY_FULL;
      float* Fm2=ws+H_FLOATS+FTY_FULL+FM_FULL;
      if(m1==8)  k_fwd_ty8<8> <<<4*Ci*16,512,0,stream>>>(h,Fty,Ci);
      else       k_fwd_ty8<12><<<4*Ci*16,512,0,stream>>>(h,Fty,Ci);
      if(m1==8)  k_fwd_x<8> <<<4*Ci,256,0,stream>>>(Fty,Fm,Ci,m2);
      else       k_fwd_x<12><<<4*Ci,256,0,stream>>>(Fty,Fm,Ci,m2);
      k_mix<<<4*4*nch,Co*8,0,stream>>>(Fm,sw[L],Fm2,Ci,Co,m1,m2);
      if(Co==24) k_pconv2<24><<<2560,256,0,stream>>>(h,cw[L],cb[L],Ci);
      else       k_pconv2<32><<<2560,256,0,stream>>>(h,cw[L],cb[L],Ci);
      k_inv_x<<<4*Co*4,256,0,stream>>>(Fm2,Fty,Co,m1,m2);     // g1 aliases Fty
      if(m1==8)  k_inv_yt8<8> <<<4*Co*16,512,0,stream>>>(Fty,h,Co,(L!=3)?1:0);
      else       k_inv_yt8<12><<<4*Co*16,512,0,stream>>>(Fty,h,Co,(L!=3)?1:0);
    } else {
      // scratch lives in d_out (rewritten entirely by k_head at the end)
      float* Fty=out;                 // <= 1,572,864 floats
      float* Fm =out+1572864;         // <=   294,912 floats
      float* Fm2=out+1867776;         // <= 1,179,648 floats (per-b strided)
      for(int b=0;b<4;b++){
        float* hbp=h+(long)b*32*SP3;
        if(m1==8)  k_fwd_ty8<8> <<<Ci*16,512,0,stream>>>(hbp,Fty,Ci);
        else       k_fwd_ty8<12><<<Ci*16,512,0,stream>>>(hbp,Fty,Ci);
        if(m1==8)  k_fwd_x<8> <<<Ci,256,0,stream>>>(Fty,Fm,Ci,m2);
        else       k_fwd_x<12><<<Ci,256,0,stream>>>(Fty,Fm,Ci,m2);
        k_mix<<<4*nch,Co*8,0,stream>>>(Fm,sw[L],Fm2+b*FM_B,Ci,Co,m1,m2);
      }
      if(Co==24) k_pconv2<24><<<2560,256,0,stream>>>(h,cw[L],cb[L],Ci);
      else       k_pconv2<32><<<2560,256,0,stream>>>(h,cw[L],cb[L],Ci);
      for(int b=0;b<4;b++){
        float* hbp=h+(long)b*32*SP3;
        k_inv_x<<<Co*4,256,0,stream>>>(Fm2+b*FM_B,Fty,Co,m1,m2);
        if(m1==8)  k_inv_yt8<8> <<<Co*16,512,0,stream>>>(Fty,hbp,Co,(L!=3)?1:0);
        else       k_inv_yt8<12><<<Co*16,512,0,stream>>>(Fty,hbp,Co,(L!=3)?1:0);
      }
    }
  }
  k_head2<<<2560,256,0,stream>>>(h,fc1w,fc1b,fc2w,fc2b,out);
}